// Round 14
// 24213.107 us; speedup vs baseline: 33.3468x; 1.2186x over previous
//
#include <hip/hip_runtime.h>
#include <math.h>

#define NN 4096      // points
#define NC 768       // feature dim
#define KK 16        // knn k
#define SK 128       // spectral basis size
#define LM 640       // Lanczos steps (5x oversampling of SK)
#define NR (LM / 128) // dots rows per block
#define LAMBDA_ 100.0f
#define DYNLDS (LM * 32 * 4 + NN * 4 + LM * 4)
#define CHOLLDS (2 * SK * (SK + 1) * 4)
#define CHSLDS (SK * (SK + 1) * 4)

typedef unsigned int u32;

__device__ __forceinline__ float hashf(u32 x) {
  x ^= x >> 16; x *= 0x7feb352dU; x ^= x >> 15; x *= 0x846ca68bU; x ^= x >> 16;
  return ((float)x) * (1.0f / 4294967296.0f);  // [0,1)
}

// ---- agent-scope access helpers ----
__device__ __forceinline__ float agld(const float* p) {
  return __hip_atomic_load((float*)p, __ATOMIC_RELAXED, __HIP_MEMORY_SCOPE_AGENT);
}
__device__ __forceinline__ void agst(float* p, float v) {
  __hip_atomic_store(p, v, __ATOMIC_RELAXED, __HIP_MEMORY_SCOPE_AGENT);
}
__device__ __forceinline__ double agldd(const double* p) {
  return __hip_atomic_load((double*)p, __ATOMIC_RELAXED, __HIP_MEMORY_SCOPE_AGENT);
}
__device__ __forceinline__ void agstd(double* p, double v) {
  __hip_atomic_store(p, v, __ATOMIC_RELAXED, __HIP_MEMORY_SCOPE_AGENT);
}

// ---- per-side two-level tree barrier ----
__device__ __forceinline__ void gbar2(unsigned* syb, int lb, unsigned gph) {
  asm volatile("s_waitcnt vmcnt(0)" ::: "memory");
  __syncthreads();
  if (threadIdx.x == 0) {
    const int grp = lb >> 4, mem = lb & 15;
    unsigned* gc  = syb + grp * 16;
    unsigned* top = syb + 144;
    unsigned* fl  = syb + 256 + grp * 16;
    __hip_atomic_fetch_add(gc, 1u, __ATOMIC_RELEASE, __HIP_MEMORY_SCOPE_AGENT);
    if (mem == 0) {
      while (__hip_atomic_load(gc, __ATOMIC_RELAXED, __HIP_MEMORY_SCOPE_AGENT) < gph * 16u)
        __builtin_amdgcn_s_sleep(1);
      __hip_atomic_fetch_add(top, 1u, __ATOMIC_RELEASE, __HIP_MEMORY_SCOPE_AGENT);
      while (__hip_atomic_load(top, __ATOMIC_RELAXED, __HIP_MEMORY_SCOPE_AGENT) < gph * 8u)
        __builtin_amdgcn_s_sleep(1);
      __hip_atomic_store(fl, gph, __ATOMIC_RELEASE, __HIP_MEMORY_SCOPE_AGENT);
    } else {
      while (__hip_atomic_load(fl, __ATOMIC_RELAXED, __HIP_MEMORY_SCOPE_AGENT) < gph)
        __builtin_amdgcn_s_sleep(1);
    }
    __builtin_amdgcn_fence(__ATOMIC_ACQUIRE, "agent");
  }
  __syncthreads();
}

// ---------- row squared norms (batched) ----------
__global__ void k_sqnorm2(const float* __restrict__ f0, const float* __restrict__ f1,
                          float* __restrict__ sq0, float* __restrict__ sq1) {
  __shared__ float red[256];
  const float* f = blockIdx.y ? f1 : f0;
  float* sq = blockIdx.y ? sq1 : sq0;
  int i = blockIdx.x;
  float s = 0.f;
  for (int c = threadIdx.x; c < NC; c += 256) { float v = f[(size_t)i * NC + c]; s += v * v; }
  red[threadIdx.x] = s; __syncthreads();
  for (int o = 128; o > 0; o >>= 1) { if (threadIdx.x < o) red[threadIdx.x] += red[threadIdx.x + o]; __syncthreads(); }
  if (threadIdx.x == 0) sq[i] = red[0];
}

// ---------- d2 panel (batched) ----------
__global__ void __launch_bounds__(256) k_d2panel2(const float* __restrict__ f0, const float* __restrict__ f1,
                                                  const float* __restrict__ sq0, const float* __restrict__ sq1,
                                                  float* __restrict__ pan0, float* __restrict__ pan1, int i0) {
  __shared__ float As[16][65], Bs[16][65];
  const float* f = blockIdx.z ? f1 : f0;
  const float* sq = blockIdx.z ? sq1 : sq0;
  float* pan = blockIdx.z ? pan1 : pan0;
  int bj = blockIdx.x, bi = blockIdx.y;
  int row0 = i0 + bi * 64, col0 = bj * 64;
  int tx = threadIdx.x & 15, ty = threadIdx.x >> 4;
  float acc[4][4] = {};
  for (int k0 = 0; k0 < NC; k0 += 16) {
    for (int t2 = threadIdx.x; t2 < 1024; t2 += 256) {
      int kk = t2 & 15, rr = t2 >> 4;
      As[kk][rr] = f[(size_t)(row0 + rr) * NC + k0 + kk];
      Bs[kk][rr] = f[(size_t)(col0 + rr) * NC + k0 + kk];
    }
    __syncthreads();
#pragma unroll
    for (int kk = 0; kk < 16; kk++) {
      float av[4], bv[4];
#pragma unroll
      for (int a = 0; a < 4; a++) av[a] = As[kk][ty * 4 + a];
#pragma unroll
      for (int b = 0; b < 4; b++) bv[b] = Bs[kk][tx * 4 + b];
#pragma unroll
      for (int a = 0; a < 4; a++)
#pragma unroll
        for (int b = 0; b < 4; b++) acc[a][b] += av[a] * bv[b];
    }
    __syncthreads();
  }
#pragma unroll
  for (int a = 0; a < 4; a++) {
    int gr = row0 + ty * 4 + a;
    int pr = bi * 64 + ty * 4 + a;
    float sr = sq[gr];
#pragma unroll
    for (int b = 0; b < 4; b++) {
      int gc = col0 + tx * 4 + b;
      float v = sr + sq[gc] - 2.f * acc[a][b];
      v = fmaxf(v, 0.f);
      if (gr == gc) v += 1e10f;
      pan[(size_t)pr * NN + gc] = v;
    }
  }
}

// ---------- top-16 smallest per row (batched) ----------
__global__ void __launch_bounds__(256) k_topk2(const float* __restrict__ pan0, const float* __restrict__ pan1,
                                               int i0,
                                               int* __restrict__ idx0, int* __restrict__ idx1,
                                               float* __restrict__ dkv0, float* __restrict__ dkv1) {
  __shared__ float vals[NN];
  __shared__ float rv[256];
  __shared__ int ri[256];
  const float* pan = blockIdx.z ? pan1 : pan0;
  int* idx = blockIdx.z ? idx1 : idx0;
  float* dkv = blockIdx.z ? dkv1 : dkv0;
  int r = blockIdx.x;
  const float* row = pan + (size_t)r * NN;
  for (int j = threadIdx.x; j < NN; j += 256) vals[j] = row[j];
  __syncthreads();
  for (int t3 = 0; t3 < KK; t3++) {
    float bv = 1e30f; int bi2 = NN;
    for (int j2 = threadIdx.x; j2 < NN; j2 += 256) {
      float v = vals[j2];
      if (v < bv || (v == bv && j2 < bi2)) { bv = v; bi2 = j2; }
    }
    rv[threadIdx.x] = bv; ri[threadIdx.x] = bi2;
    __syncthreads();
    for (int o = 128; o > 0; o >>= 1) {
      if (threadIdx.x < o) {
        float v2 = rv[threadIdx.x + o]; int i2 = ri[threadIdx.x + o];
        if (v2 < rv[threadIdx.x] || (v2 == rv[threadIdx.x] && i2 < ri[threadIdx.x])) {
          rv[threadIdx.x] = v2; ri[threadIdx.x] = i2;
        }
      }
      __syncthreads();
    }
    if (threadIdx.x == 0) {
      idx[(size_t)(i0 + r) * KK + t3] = ri[0];
      dkv[(size_t)(i0 + r) * KK + t3] = rv[0];
      vals[ri[0]] = 1e30f;
    }
    __syncthreads();
  }
}

// ---------- sigma2 (batched) ----------
__global__ void k_partsum2(const float* __restrict__ dkv0, const float* __restrict__ dkv1,
                           double* __restrict__ part) {
  __shared__ double red[256];
  const float* dkv = blockIdx.y ? dkv1 : dkv0;
  double s = 0.0;
  for (int t2 = blockIdx.x * 256 + threadIdx.x; t2 < NN * KK; t2 += 64 * 256) s += (double)dkv[t2];
  red[threadIdx.x] = s; __syncthreads();
  for (int o = 128; o > 0; o >>= 1) { if (threadIdx.x < o) red[threadIdx.x] += red[threadIdx.x + o]; __syncthreads(); }
  if (threadIdx.x == 0) part[blockIdx.y * 64 + blockIdx.x] = red[0];
}
__global__ void k_sigma2(const double* __restrict__ part, double* __restrict__ scal0,
                         double* __restrict__ scal1) {
  __shared__ double red[64];
  red[threadIdx.x] = part[blockIdx.x * 64 + threadIdx.x]; __syncthreads();
  for (int o = 32; o > 0; o >>= 1) { if (threadIdx.x < o) red[threadIdx.x] += red[threadIdx.x + o]; __syncthreads(); }
  if (threadIdx.x == 0) (blockIdx.x ? scal1 : scal0)[0] = red[0] / (double)(NN * KK) + 1e-12;
}

// ---------- gaussian weights (batched) ----------
__global__ void k_wexp2(const float* __restrict__ dkv0, const float* __restrict__ dkv1,
                        const double* __restrict__ scal0, const double* __restrict__ scal1,
                        float* __restrict__ wv0, float* __restrict__ wv1) {
  const float* dkv = blockIdx.y ? dkv1 : dkv0;
  const double* scal = blockIdx.y ? scal1 : scal0;
  float* wv = blockIdx.y ? wv1 : wv0;
  int t = blockIdx.x * 256 + threadIdx.x;
  if (t >= NN * KK) return;
  float inv2s = (float)(0.5 / scal[0]);
  wv[t] = expf(-dkv[t] * inv2s);
}

// ---------- CSR transpose: counting-sort (batched) ----------
__global__ void k_count2(const int* __restrict__ idx0, const int* __restrict__ idx1,
                         int* __restrict__ cnt) {
  const int* idx = blockIdx.y ? idx1 : idx0;
  int t = blockIdx.x * 256 + threadIdx.x;
  if (t < NN * KK) atomicAdd(&cnt[blockIdx.y * NN + idx[t]], 1);
}

__global__ void __launch_bounds__(1024) k_scan2(const int* __restrict__ cnt,
                                                int* __restrict__ roff0, int* __restrict__ roff1) {
  __shared__ int buf[1024];
  const int* c = cnt + blockIdx.x * NN;
  int* roff = blockIdx.x ? roff1 : roff0;
  int t = threadIdx.x;
  int v[4]; int s = 0;
#pragma unroll
  for (int u = 0; u < 4; u++) { v[u] = c[t * 4 + u]; s += v[u]; }
  buf[t] = s; __syncthreads();
  for (int o = 1; o < 1024; o <<= 1) {
    int x = (t >= o) ? buf[t - o] : 0;
    __syncthreads();
    buf[t] += x;
    __syncthreads();
  }
  int run = (t == 0) ? 0 : buf[t - 1];
#pragma unroll
  for (int u = 0; u < 4; u++) { roff[t * 4 + u] = run; run += v[u]; }
  if (t == 1023) roff[NN] = run;
}

__global__ void k_hist2(const int* __restrict__ idx0, const int* __restrict__ idx1,
                        int* __restrict__ hist) {
  const int* idx = blockIdx.y ? idx1 : idx0;
  int* h = hist + (size_t)blockIdx.y * 256 * NN;
  int e = blockIdx.x * 256 + threadIdx.x;
  atomicAdd(&h[(e >> 8) * NN + idx[e]], 1);
}
__global__ void k_colscan2(const int* __restrict__ hist,
                           const int* __restrict__ roff0, const int* __restrict__ roff1,
                           int* __restrict__ baseb) {
  const int* h = hist + (size_t)blockIdx.y * 256 * NN;
  const int* roff = blockIdx.y ? roff1 : roff0;
  int* bb = baseb + (size_t)blockIdx.y * 256 * NN;
  int j = blockIdx.x * 256 + threadIdx.x;
  if (j >= NN) return;
  int run = roff[j];
  for (int c = 0; c < 256; c++) { bb[c * NN + j] = run; run += h[c * NN + j]; }
}
__global__ void __launch_bounds__(256) k_place2b(const int* __restrict__ idx0, const int* __restrict__ idx1,
                                                 const int* __restrict__ baseb,
                                                 int* __restrict__ tsrc0, int* __restrict__ tsrc1) {
  __shared__ int ish[256];
  const int* idx = blockIdx.y ? idx1 : idx0;
  const int* bb = baseb + (size_t)blockIdx.y * 256 * NN;
  int* tsrc = blockIdx.y ? tsrc1 : tsrc0;
  int c = blockIdx.x;
  int e = c * 256 + threadIdx.x;
  ish[threadIdx.x] = idx[e];
  __syncthreads();
  int j = ish[threadIdx.x];
  int rank = 0;
  for (int p2 = 0; p2 < threadIdx.x; p2++) rank += (ish[p2] == j) ? 1 : 0;
  tsrc[bb[c * NN + j] + rank] = e;
}

// ---------- degrees (batched) ----------
__global__ void k_deg2(const float* __restrict__ wv0, const float* __restrict__ wv1,
                       const int* __restrict__ roff0, const int* __restrict__ roff1,
                       const int* __restrict__ tsrc0, const int* __restrict__ tsrc1,
                       float* __restrict__ deg0, float* __restrict__ deg1) {
  const float* wv = blockIdx.y ? wv1 : wv0;
  const int* roff = blockIdx.y ? roff1 : roff0;
  const int* tsrc = blockIdx.y ? tsrc1 : tsrc0;
  float* deg = blockIdx.y ? deg1 : deg0;
  int i = blockIdx.x * 256 + threadIdx.x;
  if (i >= NN) return;
  float s = 0.f;
  for (int l = 0; l < KK; l++) s += wv[(size_t)i * KK + l];
  float s2 = 0.f;
  for (int e = roff[i]; e < roff[i + 1]; e++) s2 += wv[tsrc[e]];
  deg[i] = 0.5f * (s + s2);
}

// ---------- normalized adjacency (batched) ----------
__global__ void k_wadj2b(const float* __restrict__ wv0, const float* __restrict__ wv1,
                         const int* __restrict__ idx0, const int* __restrict__ idx1,
                         const int* __restrict__ roff0, const int* __restrict__ roff1,
                         const int* __restrict__ tsrc0, const int* __restrict__ tsrc1,
                         const float* __restrict__ deg0, const float* __restrict__ deg1,
                         float* __restrict__ wadjr0, float* __restrict__ wadjr1,
                         float* __restrict__ wadjt0, float* __restrict__ wadjt1,
                         int* __restrict__ tcol0, int* __restrict__ tcol1) {
  const float* wv = blockIdx.y ? wv1 : wv0;
  const int* idx = blockIdx.y ? idx1 : idx0;
  const int* roff = blockIdx.y ? roff1 : roff0;
  const int* tsrc = blockIdx.y ? tsrc1 : tsrc0;
  const float* deg = blockIdx.y ? deg1 : deg0;
  float* wadjr = blockIdx.y ? wadjr1 : wadjr0;
  float* wadjt = blockIdx.y ? wadjt1 : wadjt0;
  int* tcol = blockIdx.y ? tcol1 : tcol0;
  int i = blockIdx.x * 256 + threadIdx.x;
  if (i >= NN) return;
  float di = 1.0f / sqrtf(deg[i] + 1e-8f);
  for (int l = 0; l < KK; l++) {
    int j = idx[(size_t)i * KK + l];
    float dj = 1.0f / sqrtf(deg[j] + 1e-8f);
    wadjr[(size_t)i * KK + l] = 0.5f * wv[(size_t)i * KK + l] * di * dj;
  }
  for (int e = roff[i]; e < roff[i + 1]; e++) {
    int s = tsrc[e];
    int sn = s / KK;
    float dj = 1.0f / sqrtf(deg[sn] + 1e-8f);
    wadjt[e] = 0.5f * wv[s] * di * dj;
    tcol[e] = sn;
  }
}

// ---------- DUAL-SIDE fused cooperative Lanczos, CGS1 ----------
__global__ void __launch_bounds__(1024) k_lanczos2(
    float* __restrict__ Q0, float* __restrict__ Q1,
    float* __restrict__ ya0, float* __restrict__ ya1,
    float* __restrict__ yb0, float* __restrict__ yb1,
    const float* __restrict__ wadjr0, const int* __restrict__ idx0,
    const float* __restrict__ wadjt0, const int* __restrict__ tcol0, const int* __restrict__ roff0,
    const float* __restrict__ wadjr1, const int* __restrict__ idx1,
    const float* __restrict__ wadjt1, const int* __restrict__ tcol1, const int* __restrict__ roff1,
    float* __restrict__ cv0, float* __restrict__ cv1, double* __restrict__ part,
    double* __restrict__ Ta0, double* __restrict__ Tb0,
    double* __restrict__ Ta1, double* __restrict__ Tb1,
    unsigned* __restrict__ sy) {
  const int b = blockIdx.x, t = threadIdx.x;
  const int s = b >> 7, lb = b & 127;
  const int n0 = lb * 32;
  const int lane = t & 63, wvid = t >> 6;
  float* Qs = s ? Q1 : Q0;
  float* ybuf0 = s ? yb0 : ya0;
  float* ybuf1 = s ? yb1 : ya1;
  const float* wadjr = s ? wadjr1 : wadjr0;
  const int* idx = s ? idx1 : idx0;
  const float* wadjt = s ? wadjt1 : wadjt0;
  const int* tcol = s ? tcol1 : tcol0;
  const int* roff = s ? roff1 : roff0;
  float* cvs = s ? cv1 : cv0;
  double* ps = part + s * 128;
  double* Ta = s ? Ta1 : Ta0;
  double* Tb = s ? Tb1 : Tb0;
  unsigned* syb = sy + s * 512;
  u32 seed = 1234567u + (u32)s * 77777u;

  extern __shared__ char dynsh[];
  float* slabsh = (float*)dynsh;
  float* ysh    = (float*)(dynsh + LM * 32 * 4);
  float* cvsh   = (float*)(dynsh + LM * 32 * 4 + NN * 4);
  __shared__ double pd[2];
  __shared__ double wl[16][NR];
  __shared__ float fredu[32][33];
  __shared__ float r2loc[32];
  unsigned gph = 0;

  if (t < 32) {
    int n = n0 + t;
    agst(&ybuf0[n], hashf((u32)n * 2246822519u + seed) - 0.5f);
  }
  __syncthreads();
  if (t == 0) {
    double ss = 0.0;
    for (int u = 0; u < 32; u++) { double v = (double)agld(&ybuf0[n0 + u]); ss += v * v; }
    agstd(&ps[lb], ss);
  }
  gbar2(syb, lb, ++gph);

  for (int it = 0; it < LM; it++) {
    float* r  = (it & 1) ? ybuf1 : ybuf0;
    float* r2 = (it & 1) ? ybuf0 : ybuf1;

    // Phase A
    {
      int b4 = t * 4;
      float a0 = agld(&r[b4]), a1 = agld(&r[b4 + 1]);
      float a2 = agld(&r[b4 + 2]), a3 = agld(&r[b4 + 3]);
      ysh[b4] = a0; ysh[b4 + 1] = a1; ysh[b4 + 2] = a2; ysh[b4 + 3] = a3;
    }
    if (t < 64) {
      double v = agldd(&ps[t]) + agldd(&ps[t + 64]);
      for (int o = 32; o > 0; o >>= 1) v += __shfl_down(v, o, 64);
      if (t == 0) pd[0] = v;
    }
    __syncthreads();
    double nrm = sqrt(pd[0]);
    if (lb == 0 && t == 0 && it > 0) agstd(&Tb[it - 1], nrm);
    float inv = (float)(1.0 / (nrm > 1e-300 ? nrm : 1e-300));
    if (t < 32) {
      int n = n0 + t;
      float qv = ysh[n] * inv;
      agst(&Qs[(size_t)it * NN + n], qv);
      slabsh[it * 32 + t] = qv;
    }
#pragma unroll
    for (int rr = 0; rr < 2; rr++) {
      int n = n0 + wvid + rr * 16;
      int rb = roff[n], re = roff[n + 1];
      int L = 16 + (re - rb);
      float acc = 0.f;
      for (int i = lane; i < L; i += 64) {
        float w, qv;
        if (i < 16) { w = wadjr[(size_t)n * KK + i]; qv = ysh[idx[(size_t)n * KK + i]] * inv; }
        else        { int e = rb + i - 16; w = wadjt[e]; qv = ysh[tcol[e]] * inv; }
        acc += w * qv;
      }
      for (int o = 32; o > 0; o >>= 1) acc += __shfl_down(acc, o, 64);
      if (lane == 0) { agst(&r2[n], acc); r2loc[wvid + rr * 16] = acc; }
    }
    gbar2(syb, lb, ++gph);

    // Phase B: dots
    {
      float4 yv4;
      int b4 = t * 4;
      yv4.x = agld(&r2[b4]); yv4.y = agld(&r2[b4 + 1]);
      yv4.z = agld(&r2[b4 + 2]); yv4.w = agld(&r2[b4 + 3]);
      double sa[NR];
#pragma unroll
      for (int rsel = 0; rsel < NR; rsel++) {
        int j = lb + rsel * 128;
        sa[rsel] = 0.0;
        if (j <= it) {
          float4 q4 = *(const float4*)&Qs[(size_t)j * NN + t * 4];
          double d = (double)q4.x * yv4.x; d += (double)q4.y * yv4.y;
          d += (double)q4.z * yv4.z; d += (double)q4.w * yv4.w;
          sa[rsel] = d;
        }
      }
#pragma unroll
      for (int rsel = 0; rsel < NR; rsel++) {
        int j = lb + rsel * 128;
        if (j <= it) {
          double sd = sa[rsel];
          for (int o = 32; o > 0; o >>= 1) sd += __shfl_down(sd, o, 64);
          if (lane == 0) wl[wvid][rsel] = sd;
        }
      }
      __syncthreads();
      if (t < NR) {
        int j = lb + t * 128;
        if (j <= it) {
          double tot = 0.0;
          for (int u = 0; u < 16; u++) tot += wl[u][t];
          agst(&cvs[j], (float)tot);
          if (j == it) agstd(&Ta[it], tot);
        }
      }
      __syncthreads();
    }
    gbar2(syb, lb, ++gph);

    // Phase C: update + next norm partial
    {
      for (int j2s = t; j2s <= it; j2s += 1024) cvsh[j2s] = agld(&cvs[j2s]);
      __syncthreads();
      int i2 = t & 31, g = t >> 5;
      float s0 = 0.f, s1 = 0.f, s2 = 0.f, s3 = 0.f;
      int j = g;
      for (; j + 96 <= it; j += 128) {
        s0 += cvsh[j]      * slabsh[j * 32 + i2];
        s1 += cvsh[j + 32] * slabsh[(j + 32) * 32 + i2];
        s2 += cvsh[j + 64] * slabsh[(j + 64) * 32 + i2];
        s3 += cvsh[j + 96] * slabsh[(j + 96) * 32 + i2];
      }
      for (; j <= it; j += 32) s0 += cvsh[j] * slabsh[j * 32 + i2];
      fredu[g][i2] = (s0 + s1) + (s2 + s3);
      __syncthreads();
      if (t < 32) {
        float acc2 = 0.f;
        for (int g2 = 0; g2 < 32; g2++) acc2 += fredu[g2][t];
        float ny = r2loc[t] - acc2;
        agst(&r2[n0 + t], ny);
        r2loc[t] = ny;
      }
      __syncthreads();
      if (t == 0) {
        double s2d = 0.0;
        for (int u = 0; u < 32; u++) { double v = (double)r2loc[u]; s2d += v * v; }
        agstd(&ps[lb], s2d);
      }
    }
    gbar2(syb, lb, ++gph);
  }
}

// ---------- bisection (batched) ----------
__global__ void __launch_bounds__(128) k_bisect2(const double* __restrict__ Ta0, const double* __restrict__ Tb0,
                                                 const double* __restrict__ Ta1, const double* __restrict__ Tb1,
                                                 double* __restrict__ theta0, double* __restrict__ theta1,
                                                 float* __restrict__ ev0, float* __restrict__ ev1) {
  __shared__ double Tas[LM];
  __shared__ double Tb2[LM];
  int side = blockIdx.x;
  const double* Ta = side ? Ta1 : Ta0;
  const double* Tb = side ? Tb1 : Tb0;
  double* theta = side ? theta1 : theta0;
  float* evL = side ? ev1 : ev0;
  int j = threadIdx.x;
  for (int k = j; k < LM; k += 128) {
    Tas[k] = Ta[k];
    double bq = (k > 0) ? Tb[k - 1] : 0.0;
    Tb2[k] = bq * bq;
  }
  __syncthreads();
  if (j >= SK) return;
  int tgt = LM - j;
  double lo = -2.0, hi = 2.0;
  for (int iter = 0; iter < 50; iter++) {
    double mid = 0.5 * (lo + hi);
    int cnt = 0; double q = 1.0;
    for (int k = 0; k < LM; k++) {
      q = Tas[k] - mid - Tb2[k] / q;
      if (q < 0.0) cnt++;
      if (fabs(q) < 1e-280) q = -1e-280;
    }
    if (cnt >= tgt) hi = mid; else lo = mid;
  }
  theta[j] = 0.5 * (lo + hi);
  evL[j] = (float)(1.0 - theta[j]);
}

// ---------- inverse iteration, 1 pass (batched) ----------
__global__ void __launch_bounds__(128) k_invit2(const double* __restrict__ Ta0, const double* __restrict__ Tb0,
                        const double* __restrict__ Ta1, const double* __restrict__ Tb1,
                        const double* __restrict__ theta0, const double* __restrict__ theta1,
                        double* __restrict__ dws, double* __restrict__ ews,
                        double* __restrict__ fws, double* __restrict__ rws,
                        float* __restrict__ Ym0, float* __restrict__ Ym1) {
  __shared__ double Tas[LM];
  __shared__ double Tbs[LM];
  int side = blockIdx.x;
  const double* Ta = side ? Ta1 : Ta0;
  const double* Tb = side ? Tb1 : Tb0;
  const double* theta = side ? theta1 : theta0;
  float* Ym = side ? Ym1 : Ym0;
  size_t off = (size_t)side * LM * SK;
  double* dw = dws + off; double* ew = ews + off;
  double* fw = fws + off; double* rw = rws + off;
  int j = threadIdx.x;
  for (int k = j; k < LM; k += 128) { Tas[k] = Ta[k]; Tbs[k] = Tb[k]; }
  __syncthreads();
  if (j >= SK) return;
  double sig = theta[j];
  for (int k = 0; k < LM; k++)
    rw[(size_t)k * SK + j] = (double)hashf((u32)k * 2654435761u + (u32)j * 40503u + 17u) - 0.5;
  {
    double dk = Tas[0] - sig;
    double ek = Tbs[0];
    double fk = 0.0;
    double rk = rw[j];
    for (int k = 0; k < LM - 1; k++) {
      double bk = Tbs[k];
      double dn = Tas[k + 1] - sig;
      double en = (k + 2 < LM) ? Tbs[k + 1] : 0.0;
      double rn = rw[(size_t)(k + 1) * SK + j];
      double dd, ee, ff, dk2, ek2, rkeep, rnext;
      if (fabs(dk) >= fabs(bk)) {
        double dsafe = (fabs(dk) > 1e-300) ? dk : 1e-300;
        double m = bk / dsafe;
        dd = dsafe; ee = ek; ff = fk;
        dk2 = dn - m * ek;
        ek2 = en - m * fk;
        rkeep = rk;
        rnext = rn - m * rk;
      } else {
        double m = dk / bk;
        dd = bk; ee = dn; ff = en;
        dk2 = ek - m * dn;
        ek2 = fk - m * en;
        rkeep = rn;
        rnext = rk - m * rn;
      }
      dw[(size_t)k * SK + j] = dd;
      ew[(size_t)k * SK + j] = ee;
      fw[(size_t)k * SK + j] = ff;
      rw[(size_t)k * SK + j] = rkeep;
      rk = rnext; dk = dk2; ek = ek2; fk = 0.0;
    }
    if (fabs(dk) < 1e-300) dk = 1e-300;
    dw[(size_t)(LM - 1) * SK + j] = dk;
    ew[(size_t)(LM - 1) * SK + j] = 0.0;
    fw[(size_t)(LM - 1) * SK + j] = 0.0;
    rw[(size_t)(LM - 1) * SK + j] = rk;
    double y1 = 0.0, y2 = 0.0, nr = 0.0;
    for (int k = LM - 1; k >= 0; k--) {
      double dv = dw[(size_t)k * SK + j];
      double yk = (rw[(size_t)k * SK + j] - ew[(size_t)k * SK + j] * y1 - fw[(size_t)k * SK + j] * y2) / dv;
      rw[(size_t)k * SK + j] = yk;
      y2 = y1; y1 = yk;
      nr += yk * yk;
    }
    double inv = 1.0 / sqrt(nr > 1e-300 ? nr : 1e-300);
    for (int k = 0; k < LM; k++) Ym[(size_t)k * SK + j] = (float)(rw[(size_t)k * SK + j] * inv);
  }
}

// ---------- Cholesky + triangular inverse (batched) ----------
__global__ void __launch_bounds__(128) k_cholinv2(const float* __restrict__ S0, const float* __restrict__ S1,
                                                  float* __restrict__ L0, float* __restrict__ L1) {
  extern __shared__ float csh[];
  float (*Ls)[SK + 1] = (float(*)[SK + 1])csh;
  float (*Li)[SK + 1] = (float(*)[SK + 1])(csh + SK * (SK + 1));
  const float* S = blockIdx.x ? S1 : S0;
  float* Linv = blockIdx.x ? L1 : L0;
  int t = threadIdx.x;
  for (int e = t; e < SK * SK; e += 128) Ls[e / SK][e % SK] = S[e];
  __syncthreads();
  for (int k = 0; k < SK; k++) {
    if (t == 0) Ls[k][k] = sqrtf(fmaxf(Ls[k][k], 1e-20f));
    __syncthreads();
    float dk = Ls[k][k];
    for (int r = k + 1 + t; r < SK; r += 128) Ls[r][k] /= dk;
    __syncthreads();
    int rem = SK - k - 1;
    for (int e = t; e < rem * rem; e += 128) {
      int r = k + 1 + e / rem, c2 = k + 1 + e % rem;
      Ls[r][c2] -= Ls[r][k] * Ls[c2][k];
    }
    __syncthreads();
  }
  {
    int c = t;
    for (int r = 0; r < c; r++) Li[r][c] = 0.f;
    Li[c][c] = 1.0f / Ls[c][c];
    for (int r = c + 1; r < SK; r++) {
      float sacc = 0.f;
      for (int k = c; k < r; k++) sacc += Ls[r][k] * Li[k][c];
      Li[r][c] = -sacc / Ls[r][r];
    }
  }
  __syncthreads();
  for (int e = t; e < SK * SK; e += 128) Linv[e] = Li[e / SK][e % SK];
}

// ---------- z-batched tiled GEMMs ----------
__global__ void __launch_bounds__(256) k_gemm_tn2(const float* __restrict__ A0, const float* __restrict__ B0, float* __restrict__ C0,
                                                  const float* __restrict__ A1, const float* __restrict__ B1, float* __restrict__ C1,
                                                  int M, int P, int Kd) {
  __shared__ float As[16][65], Bs[16][65];
  const float* A = blockIdx.z ? A1 : A0;
  const float* B = blockIdx.z ? B1 : B0;
  float* Cm = blockIdx.z ? C1 : C0;
  int bm = blockIdx.x * 64, bp = blockIdx.y * 64;
  int tx = threadIdx.x & 15, ty = threadIdx.x >> 4;
  float acc[4][4] = {};
  for (int k0 = 0; k0 < Kd; k0 += 16) {
    for (int t2 = threadIdx.x; t2 < 1024; t2 += 256) {
      int mm = t2 & 63, kk = t2 >> 6;
      As[kk][mm] = A[(size_t)(k0 + kk) * M + bm + mm];
      Bs[kk][mm] = B[(size_t)(k0 + kk) * P + bp + mm];
    }
    __syncthreads();
#pragma unroll
    for (int kk = 0; kk < 16; kk++) {
      float av[4], bv[4];
#pragma unroll
      for (int a = 0; a < 4; a++) av[a] = As[kk][ty * 4 + a];
#pragma unroll
      for (int b = 0; b < 4; b++) bv[b] = Bs[kk][tx * 4 + b];
#pragma unroll
      for (int a = 0; a < 4; a++)
#pragma unroll
        for (int b = 0; b < 4; b++) acc[a][b] += av[a] * bv[b];
    }
    __syncthreads();
  }
#pragma unroll
  for (int a = 0; a < 4; a++)
#pragma unroll
    for (int b = 0; b < 4; b++)
      Cm[(size_t)(bm + ty * 4 + a) * P + bp + tx * 4 + b] = acc[a][b];
}

__global__ void __launch_bounds__(256) k_gemm_nt2(const float* __restrict__ A0, const float* __restrict__ B0, float* __restrict__ C0,
                                                  const float* __restrict__ A1, const float* __restrict__ B1, float* __restrict__ C1,
                                                  int M, int P, int Kd) {
  __shared__ float As[16][65], Bs[16][65];
  const float* A = blockIdx.z ? A1 : A0;
  const float* B = blockIdx.z ? B1 : B0;
  float* Cm = blockIdx.z ? C1 : C0;
  int bm = blockIdx.x * 64, bp = blockIdx.y * 64;
  int tx = threadIdx.x & 15, ty = threadIdx.x >> 4;
  float acc[4][4] = {};
  for (int k0 = 0; k0 < Kd; k0 += 16) {
    for (int t2 = threadIdx.x; t2 < 1024; t2 += 256) {
      int kk = t2 & 15, mm = t2 >> 4;
      As[kk][mm] = A[(size_t)(bm + mm) * Kd + k0 + kk];
      Bs[kk][mm] = B[(size_t)(bp + mm) * Kd + k0 + kk];
    }
    __syncthreads();
#pragma unroll
    for (int kk = 0; kk < 16; kk++) {
      float av[4], bv[4];
#pragma unroll
      for (int a = 0; a < 4; a++) av[a] = As[kk][ty * 4 + a];
#pragma unroll
      for (int b = 0; b < 4; b++) bv[b] = Bs[kk][tx * 4 + b];
#pragma unroll
      for (int a = 0; a < 4; a++)
#pragma unroll
        for (int b = 0; b < 4; b++) acc[a][b] += av[a] * bv[b];
    }
    __syncthreads();
  }
#pragma unroll
  for (int a = 0; a < 4; a++)
#pragma unroll
    for (int b = 0; b < 4; b++)
      Cm[(size_t)(bm + ty * 4 + a) * P + bp + tx * 4 + b] = acc[a][b];
}

__global__ void __launch_bounds__(256) k_gemm_nn2(const float* __restrict__ A0, const float* __restrict__ B0, float* __restrict__ C0,
                                                  const float* __restrict__ A1, const float* __restrict__ B1, float* __restrict__ C1,
                                                  int M, int P, int Kd) {
  __shared__ float As[16][65], Bs[16][65];
  const float* A = blockIdx.z ? A1 : A0;
  const float* B = blockIdx.z ? B1 : B0;
  float* Cm = blockIdx.z ? C1 : C0;
  int bm = blockIdx.x * 64, bp = blockIdx.y * 64;
  int tx = threadIdx.x & 15, ty = threadIdx.x >> 4;
  float acc[4][4] = {};
  for (int k0 = 0; k0 < Kd; k0 += 16) {
    for (int t2 = threadIdx.x; t2 < 1024; t2 += 256) {
      int kk = t2 & 15, mm = t2 >> 4;
      As[kk][mm] = A[(size_t)(bm + mm) * Kd + k0 + kk];
    }
    for (int t2 = threadIdx.x; t2 < 1024; t2 += 256) {
      int mm = t2 & 63, kk = t2 >> 6;
      Bs[kk][mm] = B[(size_t)(k0 + kk) * P + bp + mm];
    }
    __syncthreads();
#pragma unroll
    for (int kk = 0; kk < 16; kk++) {
      float av[4], bv[4];
#pragma unroll
      for (int a = 0; a < 4; a++) av[a] = As[kk][ty * 4 + a];
#pragma unroll
      for (int b = 0; b < 4; b++) bv[b] = Bs[kk][tx * 4 + b];
#pragma unroll
      for (int a = 0; a < 4; a++)
#pragma unroll
        for (int b = 0; b < 4; b++) acc[a][b] += av[a] * bv[b];
    }
    __syncthreads();
  }
#pragma unroll
  for (int a = 0; a < 4; a++)
#pragma unroll
    for (int b = 0; b < 4; b++)
      Cm[(size_t)(bm + ty * 4 + a) * P + bp + tx * 4 + b] = acc[a][b];
}

// ---------- s = max(max ev_a, max ev_b) ----------
__global__ void k_smax(const float* __restrict__ ea, const float* __restrict__ eb, double* __restrict__ scal) {
  __shared__ float red[128];
  int t = threadIdx.x;
  red[t] = fmaxf(ea[t], eb[t]);
  __syncthreads();
  for (int o = 64; o > 0; o >>= 1) { if (t < o) red[t] = fmaxf(red[t], red[t + o]); __syncthreads(); }
  if (t == 0) scal[1] = (double)red[0];
}

// ---------- resolvent mask (batched: y=0 -> (ev1,ev0), y=1 -> (ev0,ev1)) ----------
__global__ void k_mask2(const float* __restrict__ ev0, const float* __restrict__ ev1,
                        const double* __restrict__ scal,
                        float* __restrict__ Dm0, float* __restrict__ Dm1) {
  const float* evr = blockIdx.y ? ev0 : ev1;
  const float* evc = blockIdx.y ? ev1 : ev0;
  float* Dm = blockIdx.y ? Dm1 : Dm0;
  int t = blockIdx.x * 256 + threadIdx.x;
  if (t >= SK * SK) return;
  int i = t / SK, j = t % SK;
  float s = (float)scal[1];
  float g1 = sqrtf(fmaxf(evc[j] / s, 0.f));
  float g2 = sqrtf(fmaxf(evr[i] / s, 0.f));
  float a2 = g2 * g2 + 1.f, a1 = g1 * g1 + 1.f;
  float re = g2 / a2 - g1 / a1;
  float im = 1.f / a2 - 1.f / a1;
  Dm[t] = re * re + im * im;
}

// ---------- per-row Cholesky solve (batched over directions) ----------
__global__ void __launch_bounds__(128) k_cholsolve2(const float* __restrict__ AAt0, const float* __restrict__ BAt0,
                                                    const float* __restrict__ Dm0, float* __restrict__ Co0,
                                                    const float* __restrict__ AAt1, const float* __restrict__ BAt1,
                                                    const float* __restrict__ Dm1, float* __restrict__ Co1) {
  extern __shared__ float Msh[];   // [SK][SK+1]
  __shared__ float xs[SK];
  const float* AAt = blockIdx.y ? AAt1 : AAt0;
  const float* BAt = blockIdx.y ? BAt1 : BAt0;
  const float* Dm = blockIdx.y ? Dm1 : Dm0;
  float* Cout = blockIdx.y ? Co1 : Co0;
  int i = blockIdx.x;
  const int LD = SK + 1;
  for (int t2 = threadIdx.x; t2 < SK * SK; t2 += 128) {
    int r = t2 / SK, c2 = t2 % SK;
    float v = AAt[t2];
    if (r == c2) v += LAMBDA_ * Dm[(size_t)i * SK + r];
    Msh[r * LD + c2] = v;
  }
  if (threadIdx.x < SK) xs[threadIdx.x] = BAt[(size_t)i * SK + threadIdx.x];
  __syncthreads();
  for (int k = 0; k < SK; k++) {
    if (threadIdx.x == 0) Msh[k * LD + k] = sqrtf(fmaxf(Msh[k * LD + k], 1e-20f));
    __syncthreads();
    float dk = Msh[k * LD + k];
    for (int r = k + 1 + threadIdx.x; r < SK; r += 128) Msh[r * LD + k] /= dk;
    __syncthreads();
    int rem = SK - k - 1;
    for (int t2 = threadIdx.x; t2 < rem * rem; t2 += 128) {
      int r = k + 1 + t2 / rem, c2 = k + 1 + t2 % rem;
      Msh[r * LD + c2] -= Msh[r * LD + k] * Msh[c2 * LD + k];
    }
    __syncthreads();
  }
  for (int k = 0; k < SK; k++) {
    if (threadIdx.x == 0) xs[k] /= Msh[k * LD + k];
    __syncthreads();
    float xv = xs[k];
    for (int r = k + 1 + threadIdx.x; r < SK; r += 128) xs[r] -= Msh[r * LD + k] * xv;
    __syncthreads();
  }
  for (int k = SK - 1; k >= 0; k--) {
    if (threadIdx.x == 0) xs[k] /= Msh[k * LD + k];
    __syncthreads();
    float xv = xs[k];
    for (int r = threadIdx.x; r < k; r += 128) xs[r] -= Msh[k * LD + r] * xv;
    __syncthreads();
  }
  for (int t2 = threadIdx.x; t2 < SK; t2 += 128) Cout[(size_t)i * SK + t2] = xs[t2];
}

// ---------- loss partials (batched pairs) ----------
__global__ void k_frob_iden2(const float* __restrict__ M0, const float* __restrict__ M1,
                             double* __restrict__ lpart, int slotbase) {
  __shared__ double red[256];
  const float* Mat = blockIdx.y ? M1 : M0;
  int slot = slotbase + blockIdx.y;
  double s = 0.0;
  for (int t2 = blockIdx.x * 256 + threadIdx.x; t2 < SK * SK; t2 += 32 * 256) {
    float v = Mat[t2] - ((t2 / SK == t2 % SK) ? 1.f : 0.f);
    s += (double)v * (double)v;
  }
  red[threadIdx.x] = s; __syncthreads();
  for (int o = 128; o > 0; o >>= 1) { if (threadIdx.x < o) red[threadIdx.x] += red[threadIdx.x + o]; __syncthreads(); }
  if (threadIdx.x == 0) lpart[slot * 32 + blockIdx.x] = red[0];
}
__global__ void k_lap2(const float* __restrict__ Cxy, const float* __restrict__ Cyx,
                       const float* __restrict__ ev0, const float* __restrict__ ev1,
                       double* __restrict__ lpart) {
  __shared__ double red[256];
  const float* Cm = blockIdx.y ? Cyx : Cxy;
  const float* evc = blockIdx.y ? ev1 : ev0;
  const float* evr = blockIdx.y ? ev0 : ev1;
  int slot = 4 + blockIdx.y;
  double s = 0.0;
  for (int t2 = blockIdx.x * 256 + threadIdx.x; t2 < SK * SK; t2 += 32 * 256) {
    int i = t2 / SK, j = t2 % SK;
    float v = Cm[t2] * (evc[j] - evr[i]);
    s += (double)v * (double)v;
  }
  red[threadIdx.x] = s; __syncthreads();
  for (int o = 128; o > 0; o >>= 1) { if (threadIdx.x < o) red[threadIdx.x] += red[threadIdx.x + o]; __syncthreads(); }
  if (threadIdx.x == 0) lpart[slot * 32 + blockIdx.x] = red[0];
}
__global__ void k_writeout(const double* __restrict__ lpart, float* __restrict__ out) {
  if (threadIdx.x == 0) {
    double b = 0.0, o = 0.0, l = 0.0;
    for (int s = 0; s < 64; s++) b += lpart[s];
    for (int s = 64; s < 128; s++) o += lpart[s];
    for (int s = 128; s < 192; s++) l += lpart[s];
    out[0] = (float)b; out[1] = (float)o; out[2] = (float)l;
  }
}

extern "C" void kernel_launch(void* const* d_in, const int* in_sizes, int n_in,
                              void* d_out, int out_size, void* d_ws, size_t ws_size,
                              hipStream_t stream) {
  const float* feats[2] = {(const float*)d_in[0], (const float*)d_in[1]};
  char* p = (char*)d_ws;
  auto alloc = [&](size_t bytes) -> void* {
    char* r = p;
    p += (bytes + 255) & ~(size_t)255;
    return (void*)r;
  };
  float* pan0  = (float*)alloc(sizeof(float) * 256 * NN);
  float* pan1  = (float*)alloc(sizeof(float) * 256 * NN);
  float* sq0   = (float*)alloc(sizeof(float) * NN);
  float* sq1   = (float*)alloc(sizeof(float) * NN);
  float* dkv0  = (float*)alloc(sizeof(float) * (size_t)NN * KK);
  float* dkv1  = (float*)alloc(sizeof(float) * (size_t)NN * KK);
  float* wv0   = (float*)alloc(sizeof(float) * (size_t)NN * KK);
  float* wv1   = (float*)alloc(sizeof(float) * (size_t)NN * KK);
  int*   cnt   = (int*)alloc(sizeof(int) * 2 * NN);
  int*   tsrc0 = (int*)alloc(sizeof(int) * (size_t)NN * KK);
  int*   tsrc1 = (int*)alloc(sizeof(int) * (size_t)NN * KK);
  float* deg0  = (float*)alloc(sizeof(float) * NN);
  float* deg1  = (float*)alloc(sizeof(float) * NN);
  int*   hist  = (int*)alloc(sizeof(int) * 2 * 256 * NN);
  int*   baseb = (int*)alloc(sizeof(int) * 2 * 256 * NN);
  int*   idxs[2];  float* wadjrs[2]; float* wadjts[2]; int* tcols[2]; int* roffs[2];
  for (int s = 0; s < 2; s++) {
    idxs[s]   = (int*)alloc(sizeof(int) * (size_t)NN * KK);
    wadjrs[s] = (float*)alloc(sizeof(float) * (size_t)NN * KK);
    wadjts[s] = (float*)alloc(sizeof(float) * (size_t)NN * KK);
    tcols[s]  = (int*)alloc(sizeof(int) * (size_t)NN * KK);
    roffs[s]  = (int*)alloc(sizeof(int) * (NN + 1));
  }
  float* Q0    = (float*)alloc(sizeof(float) * (size_t)LM * NN);
  float* Q1    = (float*)alloc(sizeof(float) * (size_t)LM * NN);
  float* ya0   = (float*)alloc(sizeof(float) * NN);
  float* ya1   = (float*)alloc(sizeof(float) * NN);
  float* yb0   = (float*)alloc(sizeof(float) * NN);
  float* yb1   = (float*)alloc(sizeof(float) * NN);
  float* cv0   = (float*)alloc(sizeof(float) * LM);
  float* cv1   = (float*)alloc(sizeof(float) * LM);
  double* part = (double*)alloc(sizeof(double) * 256);
  double* scal0= (double*)alloc(sizeof(double) * 8);
  double* scal1= (double*)alloc(sizeof(double) * 8);
  double* Ta0  = (double*)alloc(sizeof(double) * LM);
  double* Tb0  = (double*)alloc(sizeof(double) * LM);
  double* Ta1  = (double*)alloc(sizeof(double) * LM);
  double* Tb1  = (double*)alloc(sizeof(double) * LM);
  double* theta0 = (double*)alloc(sizeof(double) * SK);
  double* theta1 = (double*)alloc(sizeof(double) * SK);
  double* dws  = (double*)alloc(sizeof(double) * 2 * (size_t)LM * SK);
  double* ews  = (double*)alloc(sizeof(double) * 2 * (size_t)LM * SK);
  double* fws  = (double*)alloc(sizeof(double) * 2 * (size_t)LM * SK);
  double* rws  = (double*)alloc(sizeof(double) * 2 * (size_t)LM * SK);
  float* Ym0   = (float*)alloc(sizeof(float) * (size_t)LM * SK);
  float* Ym1   = (float*)alloc(sizeof(float) * (size_t)LM * SK);
  float* Ym2a  = (float*)alloc(sizeof(float) * (size_t)LM * SK);
  float* Ym2b  = (float*)alloc(sizeof(float) * (size_t)LM * SK);
  float* Sm0   = (float*)alloc(sizeof(float) * SK * SK);
  float* Sm1   = (float*)alloc(sizeof(float) * SK * SK);
  float* Linv0 = (float*)alloc(sizeof(float) * SK * SK);
  float* Linv1 = (float*)alloc(sizeof(float) * SK * SK);
  float* U0    = (float*)alloc(sizeof(float) * (size_t)NN * SK);
  float* U1    = (float*)alloc(sizeof(float) * (size_t)NN * SK);
  float* ev0   = (float*)alloc(sizeof(float) * SK);
  float* ev1   = (float*)alloc(sizeof(float) * SK);
  float* Ac    = (float*)alloc(sizeof(float) * (size_t)SK * NC);
  float* Bc    = (float*)alloc(sizeof(float) * (size_t)SK * NC);
  float* AAt0  = (float*)alloc(sizeof(float) * SK * SK);
  float* AAt1  = (float*)alloc(sizeof(float) * SK * SK);
  float* BAt0  = (float*)alloc(sizeof(float) * SK * SK);
  float* BAt1  = (float*)alloc(sizeof(float) * SK * SK);
  float* Dm0   = (float*)alloc(sizeof(float) * SK * SK);
  float* Dm1   = (float*)alloc(sizeof(float) * SK * SK);
  float* Cxy   = (float*)alloc(sizeof(float) * SK * SK);
  float* Cyx   = (float*)alloc(sizeof(float) * SK * SK);
  float* P1a   = (float*)alloc(sizeof(float) * SK * SK);
  float* P1b   = (float*)alloc(sizeof(float) * SK * SK);
  float* P2a   = (float*)alloc(sizeof(float) * SK * SK);
  float* P2b   = (float*)alloc(sizeof(float) * SK * SK);
  double* lpart= (double*)alloc(sizeof(double) * 192);
  unsigned* sy = (unsigned*)alloc(sizeof(unsigned) * 1024);

  hipFuncSetAttribute((const void*)k_lanczos2,
                      hipFuncAttributeMaxDynamicSharedMemorySize, DYNLDS);
  hipFuncSetAttribute((const void*)k_cholinv2,
                      hipFuncAttributeMaxDynamicSharedMemorySize, CHOLLDS);
  hipFuncSetAttribute((const void*)k_cholsolve2,
                      hipFuncAttributeMaxDynamicSharedMemorySize, CHSLDS);

  // ---- kNN distance + top-k: both sides batched ----
  k_sqnorm2<<<dim3(NN, 2), 256, 0, stream>>>(feats[0], feats[1], sq0, sq1);
  for (int p2 = 0; p2 < 16; p2++) {
    k_d2panel2<<<dim3(64, 4, 2), 256, 0, stream>>>(feats[0], feats[1], sq0, sq1, pan0, pan1, p2 * 256);
    k_topk2<<<dim3(256, 1, 2), 256, 0, stream>>>(pan0, pan1, p2 * 256,
                                                 idxs[0], idxs[1], dkv0, dkv1);
  }
  // ---- graph finish: both sides batched ----
  k_partsum2<<<dim3(64, 2), 256, 0, stream>>>(dkv0, dkv1, part);
  k_sigma2<<<2, 64, 0, stream>>>(part, scal0, scal1);
  k_wexp2<<<dim3(NN * KK / 256, 2), 256, 0, stream>>>(dkv0, dkv1, scal0, scal1, wv0, wv1);
  hipMemsetAsync(cnt, 0, sizeof(int) * 2 * NN, stream);
  k_count2<<<dim3(NN * KK / 256, 2), 256, 0, stream>>>(idxs[0], idxs[1], cnt);
  k_scan2<<<2, 1024, 0, stream>>>(cnt, roffs[0], roffs[1]);
  hipMemsetAsync(hist, 0, sizeof(int) * 2 * 256 * NN, stream);
  k_hist2<<<dim3(256, 2), 256, 0, stream>>>(idxs[0], idxs[1], hist);
  k_colscan2<<<dim3(16, 2), 256, 0, stream>>>(hist, roffs[0], roffs[1], baseb);
  k_place2b<<<dim3(256, 2), 256, 0, stream>>>(idxs[0], idxs[1], baseb, tsrc0, tsrc1);
  k_deg2<<<dim3(16, 2), 256, 0, stream>>>(wv0, wv1, roffs[0], roffs[1], tsrc0, tsrc1, deg0, deg1);
  k_wadj2b<<<dim3(16, 2), 256, 0, stream>>>(wv0, wv1, idxs[0], idxs[1], roffs[0], roffs[1],
                                            tsrc0, tsrc1, deg0, deg1,
                                            wadjrs[0], wadjrs[1], wadjts[0], wadjts[1],
                                            tcols[0], tcols[1]);

  // ---- dual-side fused cooperative Lanczos (CGS1) ----
  hipMemsetAsync(sy, 0, sizeof(unsigned) * 1024, stream);
  {
    void* args[] = {(void*)&Q0, (void*)&Q1,
                    (void*)&ya0, (void*)&ya1, (void*)&yb0, (void*)&yb1,
                    (void*)&wadjrs[0], (void*)&idxs[0], (void*)&wadjts[0], (void*)&tcols[0], (void*)&roffs[0],
                    (void*)&wadjrs[1], (void*)&idxs[1], (void*)&wadjts[1], (void*)&tcols[1], (void*)&roffs[1],
                    (void*)&cv0, (void*)&cv1, (void*)&part,
                    (void*)&Ta0, (void*)&Tb0, (void*)&Ta1, (void*)&Tb1,
                    (void*)&sy};
    hipLaunchCooperativeKernel((const void*)k_lanczos2, dim3(256), dim3(1024), args, DYNLDS, stream);
  }

  // ---- spectral finish: batched bisect + invit + CholQR2 + Ritz ----
  k_bisect2<<<2, 128, 0, stream>>>(Ta0, Tb0, Ta1, Tb1, theta0, theta1, ev0, ev1);
  k_invit2<<<2, 128, 0, stream>>>(Ta0, Tb0, Ta1, Tb1, theta0, theta1,
                                  dws, ews, fws, rws, Ym0, Ym1);
  k_gemm_tn2<<<dim3(2, 2, 2), 256, 0, stream>>>(Ym0, Ym0, Sm0, Ym1, Ym1, Sm1, SK, SK, LM);
  k_cholinv2<<<2, 128, CHOLLDS, stream>>>(Sm0, Sm1, Linv0, Linv1);
  k_gemm_nt2<<<dim3(LM / 64, 2, 2), 256, 0, stream>>>(Ym0, Linv0, Ym2a, Ym1, Linv1, Ym2b, LM, SK, SK);
  k_gemm_tn2<<<dim3(2, 2, 2), 256, 0, stream>>>(Ym2a, Ym2a, Sm0, Ym2b, Ym2b, Sm1, SK, SK, LM);
  k_cholinv2<<<2, 128, CHOLLDS, stream>>>(Sm0, Sm1, Linv0, Linv1);
  k_gemm_nt2<<<dim3(LM / 64, 2, 2), 256, 0, stream>>>(Ym2a, Linv0, Ym0, Ym2b, Linv1, Ym1, LM, SK, SK);
  k_gemm_tn2<<<dim3(NN / 64, SK / 64, 2), 256, 0, stream>>>(Q0, Ym0, U0, Q1, Ym1, U1, NN, SK, LM);

  // ---- spectral coefficients + FM solves + losses ----
  k_gemm_tn2<<<dim3(SK / 64, NC / 64, 2), 256, 0, stream>>>(U0, feats[0], Ac, U1, feats[1], Bc, SK, NC, NN);
  k_smax<<<1, 128, 0, stream>>>(ev0, ev1, scal0);

  k_gemm_nt2<<<dim3(2, 2, 2), 256, 0, stream>>>(Ac, Ac, AAt0, Bc, Bc, AAt1, SK, SK, NC);
  k_gemm_nt2<<<dim3(2, 2, 2), 256, 0, stream>>>(Bc, Ac, BAt0, Ac, Bc, BAt1, SK, SK, NC);
  k_mask2<<<dim3(64, 2), 256, 0, stream>>>(ev0, ev1, scal0, Dm0, Dm1);
  k_cholsolve2<<<dim3(SK, 2), 128, CHSLDS, stream>>>(AAt0, BAt0, Dm0, Cxy, AAt1, BAt1, Dm1, Cyx);

  k_gemm_nn2<<<dim3(2, 2, 2), 256, 0, stream>>>(Cxy, Cyx, P1a, Cyx, Cxy, P1b, SK, SK, SK);
  k_frob_iden2<<<dim3(32, 2), 256, 0, stream>>>(P1a, P1b, lpart, 0);
  k_gemm_tn2<<<dim3(2, 2, 2), 256, 0, stream>>>(Cxy, Cxy, P2a, Cyx, Cyx, P2b, SK, SK, SK);
  k_frob_iden2<<<dim3(32, 2), 256, 0, stream>>>(P2a, P2b, lpart, 2);
  k_lap2<<<dim3(32, 2), 256, 0, stream>>>(Cxy, Cyx, ev0, ev1, lpart);
  k_writeout<<<1, 64, 0, stream>>>(lpart, (float*)d_out);
}